// Round 4
// baseline (168.152 us; speedup 1.0000x reference)
//
#include <hip/hip_runtime.h>

#define TWO_M 512
#define NCOL  64
#define SK    264          // bf16 per Yt row: 256 k + 8 pad (row = 528 B, 16B-aligned)
#define SKW   132          // u32 words per Yt row
#define SL    72           // bf16 per L' row: 64 + 8 pad (row = 144 B)

typedef short short8 __attribute__((ext_vector_type(8)));
typedef float f32x4  __attribute__((ext_vector_type(4)));

static __device__ __forceinline__ unsigned short f2bf(float f) {
    unsigned int u = __builtin_bit_cast(unsigned int, f);
    return (unsigned short)((u + 0x7fffu + ((u >> 16) & 1u)) >> 16);   // RNE
}
static __device__ __forceinline__ short8 pack8(float4 a, float4 b) {
    short8 r;
    r[0] = (short)f2bf(a.x); r[1] = (short)f2bf(a.y);
    r[2] = (short)f2bf(a.z); r[3] = (short)f2bf(a.w);
    r[4] = (short)f2bf(b.x); r[5] = (short)f2bf(b.y);
    r[6] = (short)f2bf(b.z); r[7] = (short)f2bf(b.w);
    return r;
}

// swizzled bf16 fragment read: 8 contiguous bf16 at (row, k0), k0 multiple of 8
#define FRAG(row, k0) (*(const short8*)&Yt[(row) * SK + (((((k0) >> 3) ^ (((row) >> 2) & 7)) << 3))])

// One block per batch. LDS overlay:
//   Yt  bf16[64][SK] @0       (33792 B)  swizzled transpose of y chunk
//   Gl  f32 [64*64]  @33792   (16384 B)
//   Lst bf16[64][SL] @50176   ( 9216 B)  strictly-lower L' rows
//   bd  f32 [128]    @59392   (  512 B)  b_i, invd_i
__global__ __launch_bounds__(512, 4) void gs_fused(const float* __restrict__ y,
                                                   float* __restrict__ out)
{
    __shared__ __align__(16) unsigned char smem[59904];
    unsigned short* Yt   = (unsigned short*)smem;
    unsigned int*   Yt32 = (unsigned int*)smem;
    float*          Gl   = (float*)(smem + 33792);
    unsigned short* Lst  = (unsigned short*)(smem + 50176);
    float*          bd   = (float*)(smem + 59392);

    const int   batch = blockIdx.x;
    const float* Y    = y + (size_t)batch * (TWO_M * NCOL);
    const int   tid   = threadIdx.x;
    const int   wave  = tid >> 6;
    const int   lane  = tid & 63;

    f32x4 acc[2] = {f32x4{0,0,0,0}, f32x4{0,0,0,0}};
    const int arow = 16 * (wave >> 1) + (lane & 15);   // A-fragment G-row
    const int bc0  = 32 * (wave & 1) + (lane & 15);    // B-fragment G-col base
    const int koff = (lane >> 4) * 8;

    // ---------------- Phase 1: Gram via MFMA, two k-chunks of 256 ----------------
    for (int kc = 0; kc < 2; ++kc) {
        if (kc) __syncthreads();
        const float4* src = (const float4*)(Y + (size_t)kc * 256 * NCOL);
#pragma unroll
        for (int it = 0; it < 4; ++it) {
            const int g  = it * 512 + tid;    // 0..2047
            const int kp = g >> 4;            // k-pair 0..127
            const int cq = g & 15;            // float4 column quad
            const float4 va = src[kp * 32 + cq];
            const float4 vb = src[kp * 32 + 16 + cq];
            const unsigned int p0 = (unsigned int)f2bf(va.x) | ((unsigned int)f2bf(vb.x) << 16);
            const unsigned int p1 = (unsigned int)f2bf(va.y) | ((unsigned int)f2bf(vb.y) << 16);
            const unsigned int p2 = (unsigned int)f2bf(va.z) | ((unsigned int)f2bf(vb.z) << 16);
            const unsigned int p3 = (unsigned int)f2bf(va.w) | ((unsigned int)f2bf(vb.w) << 16);
            // swizzled word index: granule (kp>>2) XOR (row>>2)&7 ; row>>2 == cq for all 4 rows
            const int ws = ((((kp >> 2) ^ (cq & 7)) << 2) | (kp & 3));
            const int c0 = 4 * cq;
            Yt32[(c0 + 0) * SKW + ws] = p0;
            Yt32[(c0 + 1) * SKW + ws] = p1;
            Yt32[(c0 + 2) * SKW + ws] = p2;
            Yt32[(c0 + 3) * SKW + ws] = p3;
        }
        __syncthreads();
#pragma unroll
        for (int kb = 0; kb < 256; kb += 32) {
            const short8 afrag = FRAG(arow, kb + koff);
#pragma unroll
            for (int j = 0; j < 2; ++j) {
                const short8 bfrag = FRAG(bc0 + 16 * j, kb + koff);
                acc[j] = __builtin_amdgcn_mfma_f32_16x16x32_bf16(afrag, bfrag, acc[j], 0, 0, 0);
            }
        }
    }

    // ---------------- G slab write (disjoint per wave) ----------------
#pragma unroll
    for (int j = 0; j < 2; ++j)
#pragma unroll
        for (int reg = 0; reg < 4; ++reg) {
            const int gr = 16 * (wave >> 1) + (lane >> 4) * 4 + reg;
            const int gc = 32 * (wave & 1) + 16 * j + (lane & 15);
            Gl[gr * 64 + gc] = acc[j][reg];
        }
    __syncthreads();

    // ---------------- Phase 2: wave-0 scalar recurrence + L' generation ----------------
    if (wave == 0) {
        const int l = lane;
        const float d     = Gl[l * 64 + l];
        const float invd  = 1.0f / d;
        const float invd0 = __shfl(invd, 0);
        float T  = Gl[l] * invd0;
        float r  = T;
        float Nq = __shfl(T, 0) * invd0;
        float bj = __shfl(r, 1);
        float Lrow = (l == 0) ? invd0 : 0.f;   // L_0 = invd_0 * e_0
        Lst[l] = 0;                             // L'_0 row = 0
        for (int j = 1; j < 64; ++j) {
            const float invdj = __shfl(invd, j);
            const float Tprev = T;
            T = (Gl[j * 64 + l] - bj * Tprev) * invdj;
            const float cj = (__shfl(Tprev, j) - bj * Nq) * invdj;
            Nq = (__shfl(T, j) - bj * cj) * invdj;
            r  = T - r * cj;
            Lrow = (((l == j) ? 1.f : 0.f) - bj * Lrow) * invdj;   // L_j row
            Lst[j * SL + l] = f2bf((l == j) ? 0.f : Lrow);         // strictly-lower part
            bj = __shfl(r, (j + 1) & 63);
        }
        bd[64 + l] = invd;
    }
    __syncthreads();

    // ---------------- Phase 3: out = Y * L'^T (MFMA) + fp32 diagonal term ----------------
    // hoist L' B-fragments (cols 0..63, K=64 in 2 slices)
    short8 bL[4][2];
#pragma unroll
    for (int nt = 0; nt < 4; ++nt)
#pragma unroll
        for (int ks = 0; ks < 2; ++ks)
            bL[nt][ks] = *(const short8*)&Lst[(16 * nt + (lane & 15)) * SL + 32 * ks + (lane >> 4) * 8];
    float ivc[4];
#pragma unroll
    for (int nt = 0; nt < 4; ++nt) ivc[nt] = bd[64 + 16 * nt + (lane & 15)];

    float* outB = out + (size_t)batch * (TWO_M * NCOL);
#pragma unroll
    for (int s = 0; s < 4; ++s) {
        const int mt = wave + 8 * s;           // m-tile 0..31 (16 rows each)
        const int r0 = 16 * mt;
        // A fragments straight from global (L3-resident re-read, coalesced 16B/lane)
        const float* yb = Y + (size_t)(r0 + (lane & 15)) * NCOL + (lane >> 4) * 8;
        const float4 a00 = *(const float4*)(yb + 0);
        const float4 a01 = *(const float4*)(yb + 4);
        const float4 a10 = *(const float4*)(yb + 32);
        const float4 a11 = *(const float4*)(yb + 36);
        short8 af[2];
        af[0] = pack8(a00, a01);
        af[1] = pack8(a10, a11);
        f32x4 c[4] = {f32x4{0,0,0,0}, f32x4{0,0,0,0}, f32x4{0,0,0,0}, f32x4{0,0,0,0}};
#pragma unroll
        for (int ks = 0; ks < 2; ++ks)
#pragma unroll
            for (int nt = 0; nt < 4; ++nt)
                c[nt] = __builtin_amdgcn_mfma_f32_16x16x32_bf16(af[ks], bL[nt][ks], c[nt], 0, 0, 0);
        // diagonal term in fp32 + store (C/D layout: row=(lane>>4)*4+reg, col=lane&15)
#pragma unroll
        for (int nt = 0; nt < 4; ++nt) {
            const int col = 16 * nt + (lane & 15);
#pragma unroll
            for (int reg = 0; reg < 4; ++reg) {
                const int rr = r0 + (lane >> 4) * 4 + reg;
                outB[(size_t)rr * NCOL + col] = c[nt][reg] + ivc[nt] * Y[(size_t)rr * NCOL + col];
            }
        }
    }
}

extern "C" void kernel_launch(void* const* d_in, const int* in_sizes, int n_in,
                              void* d_out, int out_size, void* d_ws, size_t ws_size,
                              hipStream_t stream)
{
    const float* y = (const float*)d_in[0];
    float* out = (float*)d_out;
    const int B = in_sizes[0] / (TWO_M * NCOL);
    gs_fused<<<dim3(B), dim3(512), 0, stream>>>(y, out);
}

// Round 5
// 149.010 us; speedup vs baseline: 1.1285x; 1.1285x over previous
//
#include <hip/hip_runtime.h>

#define TWO_M 512
#define NCOL  64
#define SK    136        // bf16 per Yt row (128 k + 8 pad) = 272 B, 16B-aligned
#define SKW   68         // u32 words per Yt row
#define SG    68         // f32 stride of Gl rows (4 mod 32 -> 2-way slab writes)
#define SW    65         // f32 stride of Tw rows (1 mod 32 -> 2-way everywhere)

typedef short short8 __attribute__((ext_vector_type(8)));
typedef float f32x4  __attribute__((ext_vector_type(4)));

static __device__ __forceinline__ unsigned short f2bf(float f) {
    unsigned int u = __builtin_bit_cast(unsigned int, f);
    return (unsigned short)((u + 0x7fffu + ((u >> 16) & 1u)) >> 16);   // RNE
}

// swizzled bf16 fragment read: 8 contiguous bf16 at logical (row, k0), k0 % 8 == 0
#define FRAG(row, k0) (*(const short8*)&Yt[(row) * SK + ((((k0) >> 3) ^ (((row) >> 2) & 7)) << 3)])

// One block per batch. LDS overlay (total 35328 B -> 4 blocks/CU):
//   Yt bf16[64][SK] @0       (17408 B)   swizzled transpose of current y k-chunk
//   Gl f32 [64][SG] @17408   (17408 B)
//   Tw f32[128][SW] @0       (33280 B)   overlays Yt+Gl in apply phase
//   bd f32 [128]    @34816   (  512 B)
__global__ __launch_bounds__(512, 8) void gs_fused(const float* __restrict__ y,
                                                   float* __restrict__ out)
{
    __shared__ __align__(16) unsigned char smem[35328];
    unsigned short* Yt   = (unsigned short*)smem;
    unsigned int*   Yt32 = (unsigned int*)smem;
    float*          Gl   = (float*)(smem + 17408);
    float*          Tw   = (float*)smem;
    float*          bd   = (float*)(smem + 34816);

    const int   batch = blockIdx.x;
    const float* Y    = y + (size_t)batch * (TWO_M * NCOL);
    const int   tid   = threadIdx.x;
    const int   wave  = tid >> 6;
    const int   lane  = tid & 63;

    f32x4 acc[2] = {f32x4{0,0,0,0}, f32x4{0,0,0,0}};
    const int arow = 16 * (wave >> 1) + (lane & 15);   // A-fragment G-row
    const int bc0  = 32 * (wave & 1) + (lane & 15);    // B-fragment G-col base
    const int koff = (lane >> 4) * 8;

    // ---------------- Phase 1: Gram via MFMA, four k-chunks of 128 ----------------
    for (int kc = 0; kc < 4; ++kc) {
        if (kc) __syncthreads();              // prev MFMA done reading Yt
        const float4* src = (const float4*)(Y + (size_t)kc * 128 * NCOL);
#pragma unroll
        for (int it = 0; it < 2; ++it) {
            const int g  = it * 512 + tid;    // 0..1023
            const int kp = g >> 4;            // k-pair 0..63
            const int cq = g & 15;            // float4 column quad
            const float4 va = src[kp * 32 + cq];
            const float4 vb = src[kp * 32 + 16 + cq];
            const unsigned int p0 = (unsigned int)f2bf(va.x) | ((unsigned int)f2bf(vb.x) << 16);
            const unsigned int p1 = (unsigned int)f2bf(va.y) | ((unsigned int)f2bf(vb.y) << 16);
            const unsigned int p2 = (unsigned int)f2bf(va.z) | ((unsigned int)f2bf(vb.z) << 16);
            const unsigned int p3 = (unsigned int)f2bf(va.w) | ((unsigned int)f2bf(vb.w) << 16);
            // swizzle: granule (kp>>2) ^ ((row>>2)&7), row>>2 == cq for rows 4cq..4cq+3
            const int ws = ((((kp >> 2) ^ (cq & 7)) << 2) | (kp & 3));
            const int c0 = 4 * cq;
            Yt32[(c0 + 0) * SKW + ws] = p0;
            Yt32[(c0 + 1) * SKW + ws] = p1;
            Yt32[(c0 + 2) * SKW + ws] = p2;
            Yt32[(c0 + 3) * SKW + ws] = p3;
        }
        __syncthreads();
#pragma unroll
        for (int kb = 0; kb < 128; kb += 32) {
            const short8 afrag = FRAG(arow, kb + koff);
#pragma unroll
            for (int j = 0; j < 2; ++j) {
                const short8 bfrag = FRAG(bc0 + 16 * j, kb + koff);
                acc[j] = __builtin_amdgcn_mfma_f32_16x16x32_bf16(afrag, bfrag, acc[j], 0, 0, 0);
            }
        }
    }

    // ---------------- G slab write (disjoint per wave) ----------------
#pragma unroll
    for (int j = 0; j < 2; ++j)
#pragma unroll
        for (int reg = 0; reg < 4; ++reg) {
            const int gr = 16 * (wave >> 1) + (lane >> 4) * 4 + reg;
            const int gc = 32 * (wave & 1) + 16 * j + (lane & 15);
            Gl[gr * SG + gc] = acc[j][reg];
        }
    __syncthreads();

    // ---------------- Phase 2: wave-0 scalar recurrence -> bd ----------------
    if (wave == 0) {
        const int l = lane;
        const float d     = Gl[l * SG + l];
        const float invd  = 1.0f / d;
        const float invd0 = __shfl(invd, 0);
        float T  = Gl[l] * invd0;
        float r  = T;
        float Nq = __shfl(T, 0) * invd0;
        float bj = __shfl(r, 1);
        float bsave = 0.f;
        for (int j = 1; j < 64; ++j) {
            const float invdj = __shfl(invd, j);
            const float Tprev = T;
            T = (Gl[j * SG + l] - bj * Tprev) * invdj;
            const float cj = (__shfl(Tprev, j) - bj * Nq) * invdj;
            Nq = (__shfl(T, j) - bj * cj) * invdj;
            r  = T - r * cj;
            if (l == j) bsave = bj;
            bj = __shfl(r, (j + 1) & 63);
        }
        bd[l]      = bsave;
        bd[64 + l] = invd;
    }
    __syncthreads();   // bd ready; Gl/Yt dead -> Tw usable

    // ---------------- Phase 3: apply, four 128-row chunks through Tw ----------------
    for (int c = 0; c < 4; ++c) {
        if (c) __syncthreads();               // prev chunk copy-out done
        // coalesced global -> Tw (L3-resident re-read of y)
        const float4* s4 = (const float4*)(Y + (size_t)c * 128 * NCOL);
#pragma unroll
        for (int it = 0; it < 4; ++it) {
            const int g  = it * 512 + tid;    // 0..2047
            const int r  = g >> 4;
            const int cq = g & 15;
            const float4 v = s4[g];
            float* d = &Tw[r * SW + 4 * cq];
            d[0] = v.x; d[1] = v.y; d[2] = v.z; d[3] = v.w;
        }
        __syncthreads();
        // in-LDS row recurrence (rows of this chunk)
        if ((tid >> 7) == c) {
            const int r = tid & 127;
            float* p = &Tw[r * SW];
            float q = 0.f;
#pragma unroll
            for (int i = 0; i < 64; ++i) {
                q = (p[i] - bd[i] * q) * bd[64 + i];
                p[i] = q;
            }
        }
        __syncthreads();
        // coalesced Tw -> global
        float4* gdst = (float4*)(out + (size_t)batch * (TWO_M * NCOL) + (size_t)c * 128 * NCOL);
#pragma unroll
        for (int it = 0; it < 4; ++it) {
            const int g  = it * 512 + tid;
            const int r  = g >> 4;
            const int cq = g & 15;
            const float* s = &Tw[r * SW + 4 * cq];
            gdst[g] = float4{s[0], s[1], s[2], s[3]};
        }
    }
}

extern "C" void kernel_launch(void* const* d_in, const int* in_sizes, int n_in,
                              void* d_out, int out_size, void* d_ws, size_t ws_size,
                              hipStream_t stream)
{
    const float* y = (const float*)d_in[0];
    float* out = (float*)d_out;
    const int B = in_sizes[0] / (TWO_M * NCOL);
    gs_fused<<<dim3(B), dim3(512), 0, stream>>>(y, out);
}

// Round 6
// 133.955 us; speedup vs baseline: 1.2553x; 1.1124x over previous
//
#include <hip/hip_runtime.h>

#define TWO_M 512
#define NCOL  64
#define SK    136        // bf16 per Yt row (128 k + 8 pad) = 272 B
#define SKW   68         // u32 words per Yt row
#define SG    68         // f32 stride of Gl rows

typedef short short8 __attribute__((ext_vector_type(8)));
typedef float f32x4  __attribute__((ext_vector_type(4)));

static __device__ __forceinline__ unsigned int f2bf(float f) {
    unsigned int u = __builtin_bit_cast(unsigned int, f);
    return (u + 0x7fffu + ((u >> 16) & 1u)) >> 16;   // RNE
}

// swizzled bf16 fragment read: 8 contiguous bf16 at logical (row, k0), k0 % 8 == 0
#define FRAG(row, k0) (*(const short8*)&Yt[(row) * SK + ((((k0) >> 3) ^ (((row) >> 2) & 7)) << 3)])

// One block per batch. LDS (35328 B -> 4 blocks/CU):
//   Yt bf16[64][SK] @0      (17408 B)
//   Gl f32 [64][SG] @17408  (17408 B)
//   bd f32 [128]    @34816  (  512 B)   alpha_i, invd_i
__global__ __launch_bounds__(512, 8) void gs_fused(const float* __restrict__ y,
                                                   float* __restrict__ out)
{
    __shared__ __align__(16) unsigned char smem[35328];
    unsigned short* Yt   = (unsigned short*)smem;
    unsigned int*   Yt32 = (unsigned int*)smem;
    float*          Gl   = (float*)(smem + 17408);
    float*          bd   = (float*)(smem + 34816);

    const int   batch = blockIdx.x;
    const float* Y    = y + (size_t)batch * (TWO_M * NCOL);
    const int   tid   = threadIdx.x;
    const int   wave  = tid >> 6;
    const int   lane  = tid & 63;
    const int   cq    = tid & 15;

    f32x4 acc[2] = {f32x4{0,0,0,0}, f32x4{0,0,0,0}};
    const int arow = 16 * (wave >> 1) + (lane & 15);
    const int bc0  = 32 * (wave & 1) + (lane & 15);
    const int koff = (lane >> 4) * 8;

    // staging geometry (two it-slices per 128-row chunk)
    const int kp0 = tid >> 4;               // k-pair 0..31
    const int kp1 = 32 + (tid >> 4);        // k-pair 32..63
    const int ws0 = ((((kp0 >> 2) ^ (cq & 7)) << 2) | (kp0 & 3));
    const int ws1 = ((((kp1 >> 2) ^ (cq & 7)) << 2) | (kp1 & 3));
    const int c0r = 4 * cq;
    const int ia0 = kp0 * 32 + cq, ib0 = kp0 * 32 + 16 + cq;
    const int ia1 = kp1 * 32 + cq, ib1 = kp1 * 32 + 16 + cq;

    // ---------------- Phase 1: Gram via MFMA, 4 pipelined k-chunks of 128 ----------------
    float4 va0, vb0, va1, vb1;
    {
        const float4* src = (const float4*)Y;
        va0 = src[ia0]; vb0 = src[ib0];
        va1 = src[ia1]; vb1 = src[ib1];
    }
    for (int c = 0; c < 4; ++c) {
        // pack current chunk to u32 regs (frees the float4 regs)
        unsigned int pk0[4], pk1[4];
        pk0[0] = f2bf(va0.x) | (f2bf(vb0.x) << 16);
        pk0[1] = f2bf(va0.y) | (f2bf(vb0.y) << 16);
        pk0[2] = f2bf(va0.z) | (f2bf(vb0.z) << 16);
        pk0[3] = f2bf(va0.w) | (f2bf(vb0.w) << 16);
        pk1[0] = f2bf(va1.x) | (f2bf(vb1.x) << 16);
        pk1[1] = f2bf(va1.y) | (f2bf(vb1.y) << 16);
        pk1[2] = f2bf(va1.z) | (f2bf(vb1.z) << 16);
        pk1[3] = f2bf(va1.w) | (f2bf(vb1.w) << 16);
        // issue next chunk's loads now (fly under barrier + ds_write + MFMA)
        if (c < 3) {
            const float4* src = (const float4*)(Y + (size_t)(c + 1) * 128 * NCOL);
            va0 = src[ia0]; vb0 = src[ib0];
            va1 = src[ia1]; vb1 = src[ib1];
        }
        if (c) __syncthreads();               // MFMA of c-1 done reading Yt
#pragma unroll
        for (int j = 0; j < 4; ++j) {
            Yt32[(c0r + j) * SKW + ws0] = pk0[j];
            Yt32[(c0r + j) * SKW + ws1] = pk1[j];
        }
        __syncthreads();
#pragma unroll
        for (int kb = 0; kb < 128; kb += 32) {
            const short8 afrag = FRAG(arow, kb + koff);
#pragma unroll
            for (int j = 0; j < 2; ++j) {
                const short8 bfrag = FRAG(bc0 + 16 * j, kb + koff);
                acc[j] = __builtin_amdgcn_mfma_f32_16x16x32_bf16(afrag, bfrag, acc[j], 0, 0, 0);
            }
        }
    }

    // ---------------- G slab write (disjoint per wave) ----------------
#pragma unroll
    for (int j = 0; j < 2; ++j)
#pragma unroll
        for (int reg = 0; reg < 4; ++reg) {
            const int gr = 16 * (wave >> 1) + (lane >> 4) * 4 + reg;
            const int gc = 32 * (wave & 1) + 16 * j + (lane & 15);
            Gl[gr * SG + gc] = acc[j][reg];
        }
    __syncthreads();

    // ---------------- Phase 3 prefetch (before recurrence; L3-resident) ----------------
    const float4* s4 = (const float4*)Y;
    float4 pv0 = s4[tid];
    float4 pv1 = s4[512 + tid];

    // ---------------- Phase 2: wave-0 scalar recurrence -> bd (alpha, invd) ----------------
    if (wave == 0) {
        const int l = lane;
        const float d     = Gl[l * SG + l];
        const float invd  = 1.0f / d;
        const float invd0 = __shfl(invd, 0);
        float T  = Gl[l] * invd0;
        float r  = T;
        float Nq = __shfl(T, 0) * invd0;
        float bj = __shfl(r, 1);
        float bsave = 0.f;
        float grow = Gl[SG + l];               // row j=1, prefetched
        for (int j = 1; j < 64; ++j) {
            const float grow_next = Gl[(j < 63 ? j + 1 : 63) * SG + l];
            const float invdj = __shfl(invd, j);
            const float Tprev = T;
            T = (grow - bj * Tprev) * invdj;
            const float cj = (__shfl(Tprev, j) - bj * Nq) * invdj;
            Nq = (__shfl(T, j) - bj * cj) * invdj;
            r  = T - r * cj;
            if (l == j) bsave = bj;
            bj = __shfl(r, (j + 1) & 63);
            grow = grow_next;
        }
        bd[l]      = -bsave * invd;            // alpha_l
        bd[64 + l] = invd;
    }
    __syncthreads();   // bd ready; no more barriers below

    // ---------------- Phase 3: barrier-free affine-scan apply ----------------
    // cols for this lane: c0r..c0r+3 (same for all 16 row-slices)
    const float a0 = bd[c0r], a1 = bd[c0r + 1], a2 = bd[c0r + 2], a3 = bd[c0r + 3];
    const float i0 = bd[64 + c0r], i1 = bd[64 + c0r + 1], i2 = bd[64 + c0r + 2], i3 = bd[64 + c0r + 3];
    float4* o4 = (float4*)(out + (size_t)batch * (TWO_M * NCOL));

#pragma unroll
    for (int it = 0; it < 16; ++it) {
        const float4 v = (it & 1) ? pv1 : pv0;
        if (it + 2 < 16) {
            if (it & 1) pv1 = s4[(it + 2) * 512 + tid];
            else        pv0 = s4[(it + 2) * 512 + tid];
        }
        // per-lane 4-element affine composition: q_out = A*q_in + C
        const float b0 = v.x * i0, b1 = v.y * i1, b2 = v.z * i2, b3 = v.w * i3;
        float A = a0, C = b0;
        A = a1 * A; C = fmaf(a1, C, b1);
        A = a2 * A; C = fmaf(a2, C, b2);
        A = a3 * A; C = fmaf(a3, C, b3);
        // 16-lane inclusive scan of affine pairs
#pragma unroll
        for (int dlt = 1; dlt < 16; dlt <<= 1) {
            const float Ap = __shfl_up(A, dlt, 16);
            const float Cp = __shfl_up(C, dlt, 16);
            const bool ok = (cq >= dlt);
            C = ok ? fmaf(A, Cp, C) : C;
            A = ok ? (A * Ap) : A;
        }
        // exclusive carry-in (q before this lane's segment; q_{-1} = 0)
        float qin = __shfl_up(C, 1, 16);
        if (cq == 0) qin = 0.f;
        // final local recurrence + store
        const float q0 = fmaf(a0, qin, b0);
        const float q1 = fmaf(a1, q0, b1);
        const float q2 = fmaf(a2, q1, b2);
        const float q3 = fmaf(a3, q2, b3);
        o4[it * 512 + tid] = float4{q0, q1, q2, q3};
    }
}

extern "C" void kernel_launch(void* const* d_in, const int* in_sizes, int n_in,
                              void* d_out, int out_size, void* d_ws, size_t ws_size,
                              hipStream_t stream)
{
    const float* y = (const float*)d_in[0];
    float* out = (float*)d_out;
    const int B = in_sizes[0] / (TWO_M * NCOL);
    gs_fused<<<dim3(B), dim3(512), 0, stream>>>(y, out);
}